// Round 7
// baseline (150.960 us; speedup 1.0000x reference)
//
#include <hip/hip_runtime.h>
#include <hip/hip_bf16.h>

typedef __hip_bfloat16 bf16;
typedef float in_t;
typedef float out_t;
typedef __attribute__((ext_vector_type(8))) short short8;   // 8 bf16 MFMA operand
typedef __attribute__((ext_vector_type(4))) float f32x4;    // MFMA accumulator

#define CH    64
#define CIN1  32
#define CIN2  64
#define S1    186624   // 36*72*72
#define W1    5184     // 72*72
#define S2    23328    // 18*36*36
#define W2    1296     // 36*36
#define LDSTR 1297     // k_M LDS row stride (coprime with 32)
#define BSTR  104      // k_corr patch lds bf16 row stride
#define PSTR  38       // k_pool LDS row stride
#define INV_NZ (1.0f/(288.0f + 1e-5f))

static __device__ __forceinline__ unsigned short f2bu(float f) {
    bf16 h = __float2bfloat16(f);
    unsigned short u;
    __builtin_memcpy(&u, &h, 2);
    return u;
}

// ---- xq[o,s] = b[o] + sum_c w[o,c]*x[c,s]
// o-split x4 for occupancy: grid = 365 spatial-chunks x 4 o-groups; thread = 2 spatial, 16 o
__global__ __launch_bounds__(256, 4) void k_proj_x(
    const in_t* __restrict__ x, const in_t* __restrict__ w, const in_t* __restrict__ bias,
    bf16* __restrict__ xq)
{
    int bid = blockIdx.x;
    int og  = bid & 3;                         // o-group: channels og*16 .. og*16+15
    int f2  = (bid >> 2)*256 + threadIdx.x;    // float2 spatial-pair index
    if (f2 >= S1/2) return;
    const float2* x2 = reinterpret_cast<const float2*>(x);
    float2 xv[CIN1];
    #pragma unroll
    for (int c = 0; c < CIN1; ++c) xv[c] = x2[c*(S1/2) + f2];
    ushort2* xq2 = reinterpret_cast<ushort2*>(xq);
    int o0 = og*16;
    #pragma unroll 4
    for (int oi = 0; oi < 16; ++oi) {
        int o = o0 + oi;
        float b = bias[o];
        float ax = b, ay = b;
        #pragma unroll
        for (int c = 0; c < CIN1; ++c) {
            float wv = w[o*CIN1 + c];          // uniform -> s_load
            ax += wv*xv[c].x;
            ay += wv*xv[c].y;
        }
        ushort2 r = { f2bu(ax), f2bu(ay) };
        xq2[o*(S1/2) + f2] = r;
    }
}

// ---- yk: 512 blocks = 32 o-pairs x 16 spatial chunks of 1458
__global__ __launch_bounds__(256) void k_proj_y(
    const in_t* __restrict__ y, const in_t* __restrict__ w, const in_t* __restrict__ bias,
    float* __restrict__ yk)
{
    int bid   = blockIdx.x;
    int o0    = (bid >> 4) * 2;
    int chunk = bid & 15;
    int t = threadIdx.x;
    float b0 = bias[o0], b1 = bias[o0+1];
    for (int it = 0; it < 6; ++it) {
        int sl = it*256 + t;
        if (sl >= 1458) break;
        int s = chunk*1458 + sl;
        float a0 = b0, a1 = b1;
        #pragma unroll
        for (int cc = 0; cc < CIN2; ++cc) {
            float yv = y[cc*S2 + s];
            a0 += w[o0*CIN2 + cc]     * yv;
            a1 += w[(o0+1)*CIN2 + cc] * yv;
        }
        yk[o0*S2 + s]     = a0;
        yk[(o0+1)*S2 + s] = a1;
    }
}

// ---- AvgPool3d k3 s2 p1, count_include_pad=False, separable via LDS
// grid = 64ch * 18 od = 1152 blocks
__global__ __launch_bounds__(256) void k_pool(const in_t* __restrict__ z, float* __restrict__ xd)
{
    __shared__ float wp[3*72*PSTR];           // w-pooled rows, 32832 B
    int bid = blockIdx.x;
    int c  = bid / 18, od = bid - (bid/18)*18;
    int t = threadIdx.x;
    for (int row = t; row < 216; row += 256) {
        int dd = row / 72, h = row - (row/72)*72;
        int d  = 2*od - 1 + dd;
        float* wrow = &wp[(dd*72 + h)*PSTR];
        if (d < 0) {
            #pragma unroll
            for (int q = 0; q < 18; ++q)
                *reinterpret_cast<float2*>(&wrow[2*q]) = (float2){0.f, 0.f};
        } else {
            const float4* zr = reinterpret_cast<const float4*>(
                z + ((size_t)(c*36 + d))*W1 + (size_t)h*72);
            float carry = 0.f;
            #pragma unroll
            for (int q = 0; q < 18; ++q) {
                float4 u = zr[q];
                float s0 = carry + u.x + u.y;
                float s1 = u.y + u.z + u.w;
                carry = u.w;
                *reinterpret_cast<float2*>(&wrow[2*q]) = (float2){s0, s1};
            }
        }
    }
    __syncthreads();
    int base_out = c*S2 + od*W2;
    for (int idx = t; idx < 1296; idx += 256) {
        int oh = idx / 36, ow = idx - (idx/36)*36;
        int hlo = (2*oh - 1 < 0) ? 0 : 2*oh - 1;
        int hhi = 2*oh + 1;
        float s = 0.f;
        for (int h = hlo; h <= hhi; ++h)
            s += wp[h*PSTR + ow] + wp[(72 + h)*PSTR + ow] + wp[(144 + h)*PSTR + ow];
        int cd = (od == 0) ? 2 : 3;
        int chh = (oh == 0) ? 2 : 3;
        int cw = (ow == 0) ? 2 : 3;
        xd[base_out + idx] = s / (float)(cd*chh*cw);
    }
}

// ---- M[c,k1,k2] = sum_m Uxd[c,k1,m]*Uy[c,k2,m]; output bf16 zero-padded [c][96][96]
__global__ __launch_bounds__(256) void k_M(
    const float* __restrict__ xd, const float* __restrict__ yk, unsigned short* __restrict__ Mg)
{
    __shared__ float xl[3*LDSTR];
    __shared__ float yl[3*LDSTR];
    int b = blockIdx.x;
    int c = b / 9, r = b - c*9;
    int g = r / 3, h = r - g*3;
    int t = threadIdx.x;
    int t1 = t / 27, t2 = t - (t/27)*27;
    int offx[3];
    #pragma unroll
    for (int a = 0; a < 3; ++a) {
        int kl = t1*3 + a;
        offx[a] = (kl/9)*LDSTR + (kl - (kl/9)*9);
    }
    int offy = (t2/9)*LDSTR + (t2 - (t2/9)*9);
    float acc[3] = {};
    for (int ph2 = 0; ph2 < 2; ++ph2) {
        __syncthreads();
        for (int idx = t; idx < 3*W2; idx += 256) {
            int rr = idx / W2, col = idx - rr*W2;
            xl[rr*LDSTR + col] = xd[c*S2 + (ph2*9 + g*3 + rr)*W2 + col];
            yl[rr*LDSTR + col] = yk[c*S2 + (ph2*9 + h*3 + rr)*W2 + col];
        }
        __syncthreads();
        if (t < 243) {
            for (int m = 0; m < 144; ++m) {
                int cb = m*9;
                float yv = yl[cb + offy];
                #pragma unroll
                for (int a = 0; a < 3; ++a)
                    acc[a] += xl[cb + offx[a]] * yv;
            }
        }
    }
    if (t < 243) {
        #pragma unroll
        for (int a = 0; a < 3; ++a) {
            int k1 = g*27 + t1*3 + a;
            Mg[c*9216 + k1*96 + (h*27 + t2)] = f2bu(acc[a]);
        }
    }
    if (r == 0) {
        for (int idx = t; idx < 2655; idx += 256) {
            int row, col;
            if (idx < 1440) { int q = idx/96; row = 81 + q; col = idx - q*96; }
            else { int j = idx - 1440; int q = j/15; row = q; col = 81 + (j - q*15); }
            Mg[c*9216 + row*96 + col] = 0;
        }
    }
}

// ---- MFMA corr: per (channel, 192-patch chunk): C(96x192) = Mg(96x96,bf16) x Uxq^T
__global__ __launch_bounds__(256, 3) void k_corr(
    const unsigned short* __restrict__ Mg, const bf16* __restrict__ xq,
    const in_t* __restrict__ z, out_t* __restrict__ out)
{
    __shared__ __align__(16) unsigned short Pl[192*BSTR];   // 39936 B
    int bid = blockIdx.x;
    int c   = bid / 12;
    int rem = bid - c*12;
    int ph  = rem / 3;
    int ck  = rem - ph*3;
    int colbase = ck*1728;
    int t = threadIdx.x;

    for (int idx = t; idx < 192*15; idx += 256) {
        int r = idx/15;
        Pl[r*BSTR + 81 + (idx - r*15)] = 0;
    }
    const unsigned short* xqu =
        (const unsigned short*)(xq + (size_t)c*S1 + (size_t)(ph*9)*W1 + colbase);
    for (int idx = t; idx < 3888; idx += 256) {
        int i2 = idx / 432, v4 = idx - i2*432;
        ushort4 vv = *reinterpret_cast<const ushort4*>(xqu + (size_t)i2*W1 + v4*4);
        int col = v4*4;
        unsigned short uu[4] = {vv.x, vv.y, vv.z, vv.w};
        #pragma unroll
        for (int j = 0; j < 4; ++j) {
            int cc = col + j;
            int p = cc/9, j2 = cc - p*9;
            Pl[p*BSTR + i2*9 + j2] = uu[j];
        }
    }
    __syncthreads();

    int wv = t >> 6, l = t & 63;
    int lrow = l & 15, lhi = l >> 4;

    short8 bfr[3][3];
    #pragma unroll
    for (int ntl = 0; ntl < 3; ++ntl) {
        int n = (wv*3 + ntl)*16 + lrow;
        #pragma unroll
        for (int kk = 0; kk < 3; ++kk)
            bfr[ntl][kk] = *reinterpret_cast<const short8*>(&Pl[n*BSTR + kk*32 + lhi*8]);
    }

    f32x4 acc[6][3];
    #pragma unroll
    for (int mt = 0; mt < 6; ++mt)
        #pragma unroll
        for (int ntl = 0; ntl < 3; ++ntl)
            acc[mt][ntl] = (f32x4){0.f,0.f,0.f,0.f};

    const unsigned short* Mc = Mg + c*9216;
    #pragma unroll
    for (int mt = 0; mt < 6; ++mt) {
        short8 afr[3];
        #pragma unroll
        for (int kk = 0; kk < 3; ++kk)
            afr[kk] = *reinterpret_cast<const short8*>(Mc + (mt*16 + lrow)*96 + kk*32 + lhi*8);
        #pragma unroll
        for (int ntl = 0; ntl < 3; ++ntl) {
            f32x4 d = acc[mt][ntl];
            #pragma unroll
            for (int kk = 0; kk < 3; ++kk)
                d = __builtin_amdgcn_mfma_f32_16x16x32_bf16(afr[kk], bfr[ntl][kk], d, 0, 0, 0);
            acc[mt][ntl] = d;
        }
    }
    __syncthreads();

    float* stage = reinterpret_cast<float*>(Pl);
    #pragma unroll
    for (int pass = 0; pass < 2; ++pass) {
        if ((wv >> 1) == pass) {
            #pragma unroll
            for (int mt = 0; mt < 6; ++mt)
                #pragma unroll
                for (int ntl = 0; ntl < 3; ++ntl) {
                    int n = (wv*3 + ntl)*16 + lrow - pass*96;
                    #pragma unroll
                    for (int r = 0; r < 4; ++r) {
                        int m = mt*16 + lhi*4 + r;
                        if (m <= 80) {
                            int i = m/9, j = m - 9*i;
                            stage[i*864 + n*9 + j] = acc[mt][ntl][r];
                        }
                    }
                }
        }
        __syncthreads();
        for (int idx = t; idx < 1944; idx += 256) {
            int i = idx/216, c4 = idx - i*216;
            float4 sv = *reinterpret_cast<const float4*>(&stage[i*864 + c4*4]);
            int ga = c*S1 + (ph*9 + i)*W1 + colbase + pass*864 + c4*4;
            float4 dv = *reinterpret_cast<const float4*>(&z[ga]);
            float4 ov;
            float cr;
            cr = sv.x*INV_NZ; ov.x = dv.x + (cr > 0.f ? cr : 0.2f*cr)*dv.x;
            cr = sv.y*INV_NZ; ov.y = dv.y + (cr > 0.f ? cr : 0.2f*cr)*dv.y;
            cr = sv.z*INV_NZ; ov.z = dv.z + (cr > 0.f ? cr : 0.2f*cr)*dv.z;
            cr = sv.w*INV_NZ; ov.w = dv.w + (cr > 0.f ? cr : 0.2f*cr)*dv.w;
            *reinterpret_cast<float4*>(&out[ga]) = ov;
        }
        __syncthreads();
    }
}

extern "C" void kernel_launch(void* const* d_in, const int* in_sizes, int n_in,
                              void* d_out, int out_size, void* d_ws, size_t ws_size,
                              hipStream_t stream)
{
    (void)in_sizes; (void)n_in; (void)out_size; (void)ws_size;
    const in_t* x     = (const in_t*)d_in[0];
    const in_t* y     = (const in_t*)d_in[1];
    const in_t* z     = (const in_t*)d_in[2];
    const in_t* w_img = (const in_t*)d_in[3];
    const in_t* b_img = (const in_t*)d_in[4];
    const in_t* w_fea = (const in_t*)d_in[5];
    const in_t* b_fea = (const in_t*)d_in[6];
    out_t* out = (out_t*)d_out;

    char* ws = (char*)d_ws;
    bf16*           xq = (bf16*)          (ws + 0);          // 23,887,872
    float*          yk = (float*)         (ws + 23887872);   // 5,971,968
    float*          xd = (float*)         (ws + 29859840);   // 5,971,968
    unsigned short* Mg = (unsigned short*)(ws + 35831808);   // 1,179,648

    hipLaunchKernelGGL(k_proj_x, dim3(365*4), dim3(256), 0, stream, x, w_img, b_img, xq);
    hipLaunchKernelGGL(k_proj_y, dim3(512),   dim3(256), 0, stream, y, w_fea, b_fea, yk);
    hipLaunchKernelGGL(k_pool,   dim3(1152),  dim3(256), 0, stream, z, xd);
    hipLaunchKernelGGL(k_M,      dim3(576),   dim3(256), 0, stream, xd, yk, Mg);
    hipLaunchKernelGGL(k_corr,   dim3(768),   dim3(256), 0, stream, Mg, xq, z, out);
}

// Round 8
// 97.290 us; speedup vs baseline: 1.5516x; 1.5516x over previous
//
#include <hip/hip_runtime.h>
#include <hip/hip_bf16.h>

typedef __hip_bfloat16 bf16;
typedef float in_t;
typedef float out_t;
typedef __attribute__((ext_vector_type(8))) short short8;   // 8 bf16 MFMA operand
typedef __attribute__((ext_vector_type(4))) float f32x4;    // MFMA accumulator

#define CH    64
#define CIN1  32
#define CIN2  64
#define S1    186624   // 36*72*72
#define W1    5184     // 72*72
#define S2    23328    // 18*36*36
#define W2    1296     // 36*36
#define LDSTR 1297     // k_M LDS row stride (coprime with 32)
#define BSTR  104      // k_corr patch lds bf16 row stride
#define PSTR  38       // k_pool LDS row stride
#define XSTR  134      // k_proj_x LDS fp32 row stride: 8*134 % 32 == 16 -> 2-way (free)
#define INV_NZ (1.0f/(288.0f + 1e-5f))

static __device__ __forceinline__ unsigned short f2bu(float f) {
    bf16 h = __float2bfloat16(f);
    unsigned short u;
    __builtin_memcpy(&u, &h, 2);
    return u;
}

// ---- proj_x as MFMA GEMM: xq(64,S1) = W(64,32) x x(32,S1) + b, bf16 out
// grid = S1/128 = 1458 blocks; block = 256 (4 waves); per wave 2 m-tiles of 16 spatial
__global__ __launch_bounds__(256) void k_proj_x(
    const in_t* __restrict__ x, const in_t* __restrict__ w, const in_t* __restrict__ bias,
    bf16* __restrict__ xq)
{
    __shared__ float          xl[CIN1*XSTR];     // 17152 B
    __shared__ unsigned short wl[CH*CIN1];       //  4096 B
    int t   = threadIdx.x;
    int gs0 = blockIdx.x*128;

    // stage x tile [32c][128s] fp32 (coalesced float4 reads, float2 LDS writes)
    #pragma unroll
    for (int i = 0; i < 4; ++i) {
        int fi = t + i*256;                      // 0..1023
        int c  = fi >> 5, s4 = fi & 31;
        float4 v = *reinterpret_cast<const float4*>(&x[(size_t)c*S1 + gs0 + s4*4]);
        float* dst = &xl[c*XSTR + s4*4];
        *reinterpret_cast<float2*>(dst)     = (float2){v.x, v.y};
        *reinterpret_cast<float2*>(dst + 2) = (float2){v.z, v.w};
    }
    // stage W as bf16 [64o][32c]
    #pragma unroll
    for (int i = 0; i < 2; ++i) {
        int wi = t + i*256;                      // 0..511
        int o  = wi >> 3, c4 = wi & 7;
        float4 v = *reinterpret_cast<const float4*>(&w[o*CIN1 + c4*4]);
        ushort4 u = { f2bu(v.x), f2bu(v.y), f2bu(v.z), f2bu(v.w) };
        *reinterpret_cast<ushort4*>(&wl[o*CIN1 + c4*4]) = u;
    }
    int l    = t & 63, wv = t >> 6;
    int lcol = l & 15, loct = l >> 4;
    float bly[4];
    #pragma unroll
    for (int og = 0; og < 4; ++og) bly[og] = bias[og*16 + lcol];
    __syncthreads();

    // B fragments: W[o = og*16+lcol][c-octet loct]
    short8 wf[4];
    #pragma unroll
    for (int og = 0; og < 4; ++og)
        wf[og] = *reinterpret_cast<const short8*>(&wl[(og*16 + lcol)*CIN1 + loct*8]);

    #pragma unroll
    for (int mt = 0; mt < 2; ++mt) {
        int s_base = (wv*2 + mt)*16;
        // A fragment: x[c = loct*8+j][s = s_base+lcol]
        union { short8 v; unsigned short u[8]; } af;
        #pragma unroll
        for (int j = 0; j < 8; ++j)
            af.u[j] = f2bu(xl[(loct*8 + j)*XSTR + s_base + lcol]);
        #pragma unroll
        for (int og = 0; og < 4; ++og) {
            f32x4 d = { bly[og], bly[og], bly[og], bly[og] };
            d = __builtin_amdgcn_mfma_f32_16x16x32_bf16(af.v, wf[og], d, 0, 0, 0);
            // D: row(m)= loct*4+r = s, col(n)= lcol -> o ; 4 consecutive s per lane
            ushort4 r = { f2bu(d[0]), f2bu(d[1]), f2bu(d[2]), f2bu(d[3]) };
            int o = og*16 + lcol;
            *reinterpret_cast<ushort4*>(
                (unsigned short*)xq + (size_t)o*S1 + gs0 + s_base + loct*4) = r;
        }
    }
}

// ---- yk: 512 blocks = 32 o-pairs x 16 spatial chunks of 1458
__global__ __launch_bounds__(256) void k_proj_y(
    const in_t* __restrict__ y, const in_t* __restrict__ w, const in_t* __restrict__ bias,
    float* __restrict__ yk)
{
    int bid   = blockIdx.x;
    int o0    = (bid >> 4) * 2;
    int chunk = bid & 15;
    int t = threadIdx.x;
    float b0 = bias[o0], b1 = bias[o0+1];
    for (int it = 0; it < 6; ++it) {
        int sl = it*256 + t;
        if (sl >= 1458) break;
        int s = chunk*1458 + sl;
        float a0 = b0, a1 = b1;
        #pragma unroll
        for (int cc = 0; cc < CIN2; ++cc) {
            float yv = y[cc*S2 + s];
            a0 += w[o0*CIN2 + cc]     * yv;
            a1 += w[(o0+1)*CIN2 + cc] * yv;
        }
        yk[o0*S2 + s]     = a0;
        yk[(o0+1)*S2 + s] = a1;
    }
}

// ---- AvgPool3d k3 s2 p1, count_include_pad=False, separable via LDS
__global__ __launch_bounds__(256) void k_pool(const in_t* __restrict__ z, float* __restrict__ xd)
{
    __shared__ float wp[3*72*PSTR];
    int bid = blockIdx.x;
    int c  = bid / 18, od = bid - (bid/18)*18;
    int t = threadIdx.x;
    for (int row = t; row < 216; row += 256) {
        int dd = row / 72, h = row - (row/72)*72;
        int d  = 2*od - 1 + dd;
        float* wrow = &wp[(dd*72 + h)*PSTR];
        if (d < 0) {
            #pragma unroll
            for (int q = 0; q < 18; ++q)
                *reinterpret_cast<float2*>(&wrow[2*q]) = (float2){0.f, 0.f};
        } else {
            const float4* zr = reinterpret_cast<const float4*>(
                z + ((size_t)(c*36 + d))*W1 + (size_t)h*72);
            float carry = 0.f;
            #pragma unroll
            for (int q = 0; q < 18; ++q) {
                float4 u = zr[q];
                float s0 = carry + u.x + u.y;
                float s1 = u.y + u.z + u.w;
                carry = u.w;
                *reinterpret_cast<float2*>(&wrow[2*q]) = (float2){s0, s1};
            }
        }
    }
    __syncthreads();
    int base_out = c*S2 + od*W2;
    for (int idx = t; idx < 1296; idx += 256) {
        int oh = idx / 36, ow = idx - (idx/36)*36;
        int hlo = (2*oh - 1 < 0) ? 0 : 2*oh - 1;
        int hhi = 2*oh + 1;
        float s = 0.f;
        for (int h = hlo; h <= hhi; ++h)
            s += wp[h*PSTR + ow] + wp[(72 + h)*PSTR + ow] + wp[(144 + h)*PSTR + ow];
        int cd = (od == 0) ? 2 : 3;
        int chh = (oh == 0) ? 2 : 3;
        int cw = (ow == 0) ? 2 : 3;
        xd[base_out + idx] = s / (float)(cd*chh*cw);
    }
}

// ---- M[c,k1,k2] = sum_m Uxd[c,k1,m]*Uy[c,k2,m]; output bf16 zero-padded [c][96][96]
__global__ __launch_bounds__(256) void k_M(
    const float* __restrict__ xd, const float* __restrict__ yk, unsigned short* __restrict__ Mg)
{
    __shared__ float xl[3*LDSTR];
    __shared__ float yl[3*LDSTR];
    int b = blockIdx.x;
    int c = b / 9, r = b - c*9;
    int g = r / 3, h = r - g*3;
    int t = threadIdx.x;
    int t1 = t / 27, t2 = t - (t/27)*27;
    int offx[3];
    #pragma unroll
    for (int a = 0; a < 3; ++a) {
        int kl = t1*3 + a;
        offx[a] = (kl/9)*LDSTR + (kl - (kl/9)*9);
    }
    int offy = (t2/9)*LDSTR + (t2 - (t2/9)*9);
    float acc[3] = {};
    for (int ph2 = 0; ph2 < 2; ++ph2) {
        __syncthreads();
        for (int idx = t; idx < 3*W2; idx += 256) {
            int rr = idx / W2, col = idx - rr*W2;
            xl[rr*LDSTR + col] = xd[c*S2 + (ph2*9 + g*3 + rr)*W2 + col];
            yl[rr*LDSTR + col] = yk[c*S2 + (ph2*9 + h*3 + rr)*W2 + col];
        }
        __syncthreads();
        if (t < 243) {
            for (int m = 0; m < 144; ++m) {
                int cb = m*9;
                float yv = yl[cb + offy];
                #pragma unroll
                for (int a = 0; a < 3; ++a)
                    acc[a] += xl[cb + offx[a]] * yv;
            }
        }
    }
    if (t < 243) {
        #pragma unroll
        for (int a = 0; a < 3; ++a) {
            int k1 = g*27 + t1*3 + a;
            Mg[c*9216 + k1*96 + (h*27 + t2)] = f2bu(acc[a]);
        }
    }
    if (r == 0) {
        for (int idx = t; idx < 2655; idx += 256) {
            int row, col;
            if (idx < 1440) { int q = idx/96; row = 81 + q; col = idx - q*96; }
            else { int j = idx - 1440; int q = j/15; row = q; col = 81 + (j - q*15); }
            Mg[c*9216 + row*96 + col] = 0;
        }
    }
}

// ---- MFMA corr: per (channel, 192-patch chunk): C(96x192) = Mg(96x96,bf16) x Uxq^T
__global__ __launch_bounds__(256, 3) void k_corr(
    const unsigned short* __restrict__ Mg, const bf16* __restrict__ xq,
    const in_t* __restrict__ z, out_t* __restrict__ out)
{
    __shared__ __align__(16) unsigned short Pl[192*BSTR];   // 39936 B
    int bid = blockIdx.x;
    int c   = bid / 12;
    int rem = bid - c*12;
    int ph  = rem / 3;
    int ck  = rem - ph*3;
    int colbase = ck*1728;
    int t = threadIdx.x;

    for (int idx = t; idx < 192*15; idx += 256) {
        int r = idx/15;
        Pl[r*BSTR + 81 + (idx - r*15)] = 0;
    }
    const unsigned short* xqu =
        (const unsigned short*)(xq + (size_t)c*S1 + (size_t)(ph*9)*W1 + colbase);
    for (int idx = t; idx < 3888; idx += 256) {
        int i2 = idx / 432, v4 = idx - i2*432;
        ushort4 vv = *reinterpret_cast<const ushort4*>(xqu + (size_t)i2*W1 + v4*4);
        int col = v4*4;
        unsigned short uu[4] = {vv.x, vv.y, vv.z, vv.w};
        #pragma unroll
        for (int j = 0; j < 4; ++j) {
            int cc = col + j;
            int p = cc/9, j2 = cc - p*9;
            Pl[p*BSTR + i2*9 + j2] = uu[j];
        }
    }
    __syncthreads();

    int wv = t >> 6, l = t & 63;
    int lrow = l & 15, lhi = l >> 4;

    short8 bfr[3][3];
    #pragma unroll
    for (int ntl = 0; ntl < 3; ++ntl) {
        int n = (wv*3 + ntl)*16 + lrow;
        #pragma unroll
        for (int kk = 0; kk < 3; ++kk)
            bfr[ntl][kk] = *reinterpret_cast<const short8*>(&Pl[n*BSTR + kk*32 + lhi*8]);
    }

    f32x4 acc[6][3];
    #pragma unroll
    for (int mt = 0; mt < 6; ++mt)
        #pragma unroll
        for (int ntl = 0; ntl < 3; ++ntl)
            acc[mt][ntl] = (f32x4){0.f,0.f,0.f,0.f};

    const unsigned short* Mc = Mg + c*9216;
    #pragma unroll
    for (int mt = 0; mt < 6; ++mt) {
        short8 afr[3];
        #pragma unroll
        for (int kk = 0; kk < 3; ++kk)
            afr[kk] = *reinterpret_cast<const short8*>(Mc + (mt*16 + lrow)*96 + kk*32 + lhi*8);
        #pragma unroll
        for (int ntl = 0; ntl < 3; ++ntl) {
            f32x4 d = acc[mt][ntl];
            #pragma unroll
            for (int kk = 0; kk < 3; ++kk)
                d = __builtin_amdgcn_mfma_f32_16x16x32_bf16(afr[kk], bfr[ntl][kk], d, 0, 0, 0);
            acc[mt][ntl] = d;
        }
    }
    __syncthreads();

    float* stage = reinterpret_cast<float*>(Pl);
    #pragma unroll
    for (int pass = 0; pass < 2; ++pass) {
        if ((wv >> 1) == pass) {
            #pragma unroll
            for (int mt = 0; mt < 6; ++mt)
                #pragma unroll
                for (int ntl = 0; ntl < 3; ++ntl) {
                    int n = (wv*3 + ntl)*16 + lrow - pass*96;
                    #pragma unroll
                    for (int r = 0; r < 4; ++r) {
                        int m = mt*16 + lhi*4 + r;
                        if (m <= 80) {
                            int i = m/9, j = m - 9*i;
                            stage[i*864 + n*9 + j] = acc[mt][ntl][r];
                        }
                    }
                }
        }
        __syncthreads();
        for (int idx = t; idx < 1944; idx += 256) {
            int i = idx/216, c4 = idx - i*216;
            float4 sv = *reinterpret_cast<const float4*>(&stage[i*864 + c4*4]);
            int ga = c*S1 + (ph*9 + i)*W1 + colbase + pass*864 + c4*4;
            float4 dv = *reinterpret_cast<const float4*>(&z[ga]);
            float4 ov;
            float cr;
            cr = sv.x*INV_NZ; ov.x = dv.x + (cr > 0.f ? cr : 0.2f*cr)*dv.x;
            cr = sv.y*INV_NZ; ov.y = dv.y + (cr > 0.f ? cr : 0.2f*cr)*dv.y;
            cr = sv.z*INV_NZ; ov.z = dv.z + (cr > 0.f ? cr : 0.2f*cr)*dv.z;
            cr = sv.w*INV_NZ; ov.w = dv.w + (cr > 0.f ? cr : 0.2f*cr)*dv.w;
            *reinterpret_cast<float4*>(&out[ga]) = ov;
        }
        __syncthreads();
    }
}

extern "C" void kernel_launch(void* const* d_in, const int* in_sizes, int n_in,
                              void* d_out, int out_size, void* d_ws, size_t ws_size,
                              hipStream_t stream)
{
    (void)in_sizes; (void)n_in; (void)out_size; (void)ws_size;
    const in_t* x     = (const in_t*)d_in[0];
    const in_t* y     = (const in_t*)d_in[1];
    const in_t* z     = (const in_t*)d_in[2];
    const in_t* w_img = (const in_t*)d_in[3];
    const in_t* b_img = (const in_t*)d_in[4];
    const in_t* w_fea = (const in_t*)d_in[5];
    const in_t* b_fea = (const in_t*)d_in[6];
    out_t* out = (out_t*)d_out;

    char* ws = (char*)d_ws;
    bf16*           xq = (bf16*)          (ws + 0);          // 23,887,872
    float*          yk = (float*)         (ws + 23887872);   // 5,971,968
    float*          xd = (float*)         (ws + 29859840);   // 5,971,968
    unsigned short* Mg = (unsigned short*)(ws + 35831808);   // 1,179,648

    hipLaunchKernelGGL(k_proj_x, dim3(1458), dim3(256), 0, stream, x, w_img, b_img, xq);
    hipLaunchKernelGGL(k_proj_y, dim3(512),  dim3(256), 0, stream, y, w_fea, b_fea, yk);
    hipLaunchKernelGGL(k_pool,   dim3(1152), dim3(256), 0, stream, z, xd);
    hipLaunchKernelGGL(k_M,      dim3(576),  dim3(256), 0, stream, xd, yk, Mg);
    hipLaunchKernelGGL(k_corr,   dim3(768),  dim3(256), 0, stream, Mg, xq, z, out);
}